// Round 8
// baseline (527.557 us; speedup 1.0000x reference)
//
#include <hip/hip_runtime.h>
#include <hip/hip_bf16.h>

// ---------------- problem constants ----------------
#define B_    256
#define T_    250
#define NIN   700
#define NHID  512
#define NOUT  20
#define KT_N  11                 // k-tiles of 64 per segment: 704 = 11*64
#define M_TOT (B_ * T_)          // 64000

typedef float  f32x2  __attribute__((ext_vector_type(2)));
typedef float  f32x4  __attribute__((ext_vector_type(4)));
typedef float  f32x16 __attribute__((ext_vector_type(16)));
typedef int    i32x2  __attribute__((ext_vector_type(2)));
typedef int    i32x4  __attribute__((ext_vector_type(4)));
typedef int    i32x8  __attribute__((ext_vector_type(8)));

// ---------------- workspace layout ----------------
// [0, 65,536,000)   : i_in  (M_TOT x NHID bf16)
// [+, 1,441,792)    : Bpack fp8 fragment-major (4 segs)
// [+, 1,048,576)    : w_recT (512x512 f32)
// total ~68 MB
#define IIN_BYTES   ((size_t)M_TOT * NHID * 2)
#define BPACK_OFF   IIN_BYTES
#define BPACK_BYTES ((size_t)4 * KT_N * 16 * 64 * 32)
#define BPACK_WORDS (BPACK_BYTES / 4)                  // 360,448
#define WRECT_OFF   (BPACK_OFF + BPACK_BYTES)
#define BSEG        (KT_N * 16 * 512)                  // 90,112 words per B seg

// ---------------- kernel 1: pack B to fp8 fragment-major + transpose w_rec ----------------
__global__ __launch_bounds__(256) void kan_pack(
    const float* __restrict__ w_kan, const float* __restrict__ d1,
    const float* __restrict__ d2,    const float* __restrict__ d3,
    const float* __restrict__ w_rec,
    int* __restrict__ BpackW, float* __restrict__ wrecT)
{
    int idx = blockIdx.x * 256 + threadIdx.x;
    if (idx < (int)BPACK_WORDS) {
        int w   = idx;
        int c   = w >> 3;                  // 32-byte chunk index
        int jj  = (w & 7) * 4;             // byte offset within chunk
        int ln  = c & 31;
        int kh  = (c >> 5) & 1;
        int nt  = (c >> 6) & 15;
        int ks  = c >> 10;                 // seg*11 + kt
        int kt  = ks % 11;
        int seg = ks / 11;
        int n   = nt * 32 + ln;
        int kb  = kt * 64 + kh * 32 + jj;
        const float* wp = (seg == 0) ? w_kan : (seg == 1) ? d1 : (seg == 2) ? d2 : d3;
        float f0 = (kb + 0 < NIN) ? wp[(size_t)n * NIN + kb + 0] : 0.0f;
        float f1 = (kb + 1 < NIN) ? wp[(size_t)n * NIN + kb + 1] : 0.0f;
        float f2 = (kb + 2 < NIN) ? wp[(size_t)n * NIN + kb + 2] : 0.0f;
        float f3 = (kb + 3 < NIN) ? wp[(size_t)n * NIN + kb + 3] : 0.0f;
        int u = __builtin_amdgcn_cvt_pk_fp8_f32(f0, f1, 0, false);
        u     = __builtin_amdgcn_cvt_pk_fp8_f32(f2, f3, u, true);
        BpackW[w] = u;
    }
    if (idx < NHID * NHID) {
        int h  = idx & 511;
        int hp = idx >> 9;
        wrecT[(size_t)hp * NHID + h] = w_rec[(size_t)h * NHID + hp];
    }
}

// ---- pack 16 f32 -> 16 fp8 bytes (4 words) ----
__device__ __forceinline__ i32x4 pack16(const float* s) {
    i32x4 w;
    #pragma unroll
    for (int j = 0; j < 4; ++j) {
        int u = __builtin_amdgcn_cvt_pk_fp8_f32(s[4 * j + 0], s[4 * j + 1], 0, false);
        u     = __builtin_amdgcn_cvt_pk_fp8_f32(s[4 * j + 2], s[4 * j + 3], u, true);
        w[j] = u;
    }
    return w;
}

// ---- 32 f32 (one lane's k-slice) -> 4 seg A-fragments (i32x8 each) ----
__device__ __forceinline__ void cvt4(const f32x4 v[8], i32x8 A[4]) {
    float e[32];
    #pragma unroll
    for (int c = 0; c < 8; ++c) {
        e[c * 4 + 0] = v[c][0]; e[c * 4 + 1] = v[c][1];
        e[c * 4 + 2] = v[c][2]; e[c * 4 + 3] = v[c][3];
    }
    {   i32x4 lo = pack16(e), hi = pack16(e + 16);
        A[0] = i32x8{lo[0], lo[1], lo[2], lo[3], hi[0], hi[1], hi[2], hi[3]}; }
    float p1[32];
    #pragma unroll
    for (int i = 0; i < 32; ++i) p1[i] = fminf(fabsf(e[i]), 1.0f);
    {   i32x4 lo = pack16(p1), hi = pack16(p1 + 16);
        A[1] = i32x8{lo[0], lo[1], lo[2], lo[3], hi[0], hi[1], hi[2], hi[3]}; }
    float p2[32];
    #pragma unroll
    for (int i = 0; i < 32; ++i) p2[i] = p1[i] * p1[i];
    {   i32x4 lo = pack16(p2), hi = pack16(p2 + 16);
        A[2] = i32x8{lo[0], lo[1], lo[2], lo[3], hi[0], hi[1], hi[2], hi[3]}; }
    float p3[32];
    #pragma unroll
    for (int i = 0; i < 32; ++i) p3[i] = p2[i] * p1[i];
    {   i32x4 lo = pack16(p3), hi = pack16(p3 + 16);
        A[3] = i32x8{lo[0], lo[1], lo[2], lo[3], hi[0], hi[1], hi[2], hi[3]}; }
}

// ---- load one lane's 32-float k-slice (chunk-masked at the k=704 tail) ----
__device__ __forceinline__ void loadx(const float* xr, int kbase, f32x4 v[8]) {
    #pragma unroll
    for (int c = 0; c < 8; ++c) {
        int k = kbase + c * 4;
        v[c] = (k + 3 < NIN) ? *(const f32x4*)(xr + k) : f32x4{0.f, 0.f, 0.f, 0.f};
    }
}

// ---------------- kernel 2: FUSED x->fp8 + GEMM, single-wave barrier-free blocks --------
// R2-R7 post-mortem: every LDS/barrier structure landed at 19-26% MfmaUtil; the only
// issue-saturated kernel was R0 (VALU 70 + MFMA 30), whose mix was VALU-dominant.
// Mechanism: one wave's MFMA occupies the matrix pipe ~69cy but costs only a few
// issue cycles -- a single wave whose OTHER issue stream (~1100cy/kt) is shorter
// than its matrix time (32 MFMA = 2200cy/kt) hides everything itself.
// Block = 1 wave = 64 rows x 128 cols (acc[2][4]=128 VGPR, 8 indep chains).
// A converted in-register from x (read once, conversion duplicated only x4);
// B streamed from L2 (1.4GB agg ~ 23TB/s < 34.5 ceiling). No LDS, no barriers.
// __launch_bounds__(64,1): ~320 VGPR, no spill, 1 wave/SIMD.
__global__ __launch_bounds__(64, 1) void kan_gemm(
    const float* __restrict__ x, const int* __restrict__ Bpack,
    __bf16* __restrict__ iin)
{
    const int lane = threadIdx.x;
    const int l31  = lane & 31;
    const int kh   = lane >> 5;
    const int id   = blockIdx.x;     // 0..3999
    const int cfg  = id & 3;         // col group: cols cfg*128..+127
    const int by   = id >> 2;        // row group: rows by*64..+63

    // lane (kh,l31) owns rows mc*32+l31, k-slice kh*32..+31 of each kt
    const float* xr0 = x + (size_t)(by * 64 + l31) * NIN;
    const float* xr1 = xr0 + (size_t)32 * NIN;

    f32x16 acc[2][4];                // [mc][cf]
    #pragma unroll
    for (int m = 0; m < 2; ++m)
        #pragma unroll
        for (int c = 0; c < 4; ++c)
            #pragma unroll
            for (int r = 0; r < 16; ++r)
                acc[m][c][r] = 0.0f;

    i32x8 As0[4], As1[4];            // current kt A-fragments per seg, mc0/mc1

    // ---- prologue: load+convert kt=0 ----
    {
        f32x4 xb0[8], xb1[8];
        loadx(xr0, kh * 32, xb0);
        loadx(xr1, kh * 32, xb1);
        cvt4(xb0, As0);
        cvt4(xb1, As1);
    }

    #pragma unroll 1
    for (int kt = 0; kt < KT_N; ++kt) {
        // ---- prefetch next k-slice (loads retire during this kt's MFMAs) ----
        f32x4 xb0[8], xb1[8];
        if (kt + 1 < KT_N) {
            loadx(xr0, (kt + 1) * 64 + kh * 32, xb0);
            loadx(xr1, (kt + 1) * 64 + kh * 32, xb1);
        }

        // ---- 32 MFMAs: 4 segs x 4 col-frags x 2 mc (B streamed from L2) ----
        const int* bb = Bpack + (size_t)(kt * 16 + cfg * 4) * 512 + lane * 8;
        #pragma unroll
        for (int s = 0; s < 4; ++s) {
            #pragma unroll
            for (int c = 0; c < 4; ++c) {
                i32x8 b = *(const i32x8*)(bb + (size_t)s * BSEG + c * 512);
                acc[0][c] = __builtin_amdgcn_mfma_scale_f32_32x32x64_f8f6f4(
                    As0[s], b, acc[0][c], 0, 0, 0, 0x7f7f7f7f, 0, 0x7f7f7f7f);
                acc[1][c] = __builtin_amdgcn_mfma_scale_f32_32x32x64_f8f6f4(
                    As1[s], b, acc[1][c], 0, 0, 0, 0x7f7f7f7f, 0, 0x7f7f7f7f);
            }
        }

        // ---- convert next kt (VALU issue hides under the matrix pipe) ----
        if (kt + 1 < KT_N) {
            cvt4(xb0, As0);
            cvt4(xb1, As1);
        }
    }

    // ---- epilogue: 32x32 C/D layout col=lane&31, row=(r&3)+8*(r>>2)+4*(lane>>5) ----
    #pragma unroll
    for (int m = 0; m < 2; ++m) {
        int m0 = by * 64 + m * 32 + kh * 4;
        #pragma unroll
        for (int c = 0; c < 4; ++c) {
            int col = cfg * 128 + c * 32 + l31;
            #pragma unroll
            for (int r = 0; r < 16; ++r) {
                int row = m0 + (r & 3) + 8 * (r >> 2);
                iin[(size_t)row * NHID + col] = (__bf16)acc[m][c][r];
            }
        }
    }
}

// ---------------- kernel 3: adaptive-LIF scan, one wave per sample, PF=25 bf16 ----------------
#define PF 25
__global__ __launch_bounds__(64) void kan_scan(
    const __bf16* __restrict__ iin, const float* __restrict__ wrecT,
    const float* __restrict__ w_out, float* __restrict__ out)
{
    const int b    = blockIdx.x;
    const int lane = threadIdx.x;
    const __bf16* basep = iin + (size_t)b * T_ * NHID + lane * 8;
    #define LOADQ(t) (*(const i32x4*)(basep + (size_t)(t) * NHID))

    i32x4 q[PF];
    #pragma unroll
    for (int d = 0; d < PF; ++d) q[d] = LOADQ(d);

    float v1[8], a1[8];
    #pragma unroll
    for (int u = 0; u < 8; ++u) { v1[u] = 0.f; a1[u] = 0.f; }
    unsigned sm = 0;
    int anyprev = 0;
    float v_out = 0.f, acco = 0.f;

    #pragma unroll 1
    for (int t0 = 0; t0 < T_; t0 += PF) {
        #pragma unroll
        for (int j = 0; j < PF; ++j) {
            const int t = t0 + j;
            float cur[8];
            #pragma unroll
            for (int w = 0; w < 4; ++w) {
                int wv = q[j][w];
                cur[2 * w]     = __builtin_bit_cast(float, wv << 16);
                cur[2 * w + 1] = __builtin_bit_cast(float, wv & 0xffff0000);
            }
            if (t + PF < T_) q[j] = LOADQ(t + PF);

            if (anyprev) {           // rare path: recurrent input from prev spikes
                #pragma unroll
                for (int u = 0; u < 8; ++u) {
                    unsigned long long mu = __ballot((sm >> u) & 1u);
                    while (mu) {
                        int jl = __ffsll(mu) - 1; mu &= mu - 1;
                        const float* wr = wrecT + (size_t)(jl * 8 + u) * NHID + lane * 8;
                        f32x4 wa = *(const f32x4*)wr;
                        f32x4 wb = *(const f32x4*)(wr + 4);
                        cur[0] += wa[0]; cur[1] += wa[1]; cur[2] += wa[2]; cur[3] += wa[3];
                        cur[4] += wb[0]; cur[5] += wb[1]; cur[6] += wb[2]; cur[7] += wb[3];
                    }
                }
            }

            unsigned nm = 0;
            #pragma unroll
            for (int u = 0; u < 8; ++u) {
                float sp = ((sm >> u) & 1u) ? 1.0f : 0.0f;
                v1[u] = 0.95f * v1[u] + 0.05f * cur[u] - sp;
                a1[u] = 0.85f * a1[u] + 0.15f * sp;
                if (v1[u] - (1.0f + 0.05f * a1[u]) > 0.0f) nm |= (1u << u);
            }

            unsigned long long anyb = __ballot(nm != 0u);
            float io = 0.0f;
            if (anyb) {              // rare path: readout current from spikes
                #pragma unroll
                for (int u = 0; u < 8; ++u) {
                    unsigned long long mu = __ballot((nm >> u) & 1u);
                    while (mu) {
                        int jl = __ffsll(mu) - 1; mu &= mu - 1;
                        int unit = jl * 8 + u;
                        if (lane < NOUT) io += w_out[(size_t)lane * NHID + unit];
                    }
                }
            }

            v_out = 0.9f * v_out + io;
            float so = (v_out - 1.0f > 0.0f) ? 1.0f : 0.0f;
            v_out -= so;
            acco += v_out;

            sm = nm;
            anyprev = (anyb != 0ull);
        }
    }

    if (lane < NOUT) out[b * NOUT + lane] = acco * (1.0f / 250.0f);
}

// ---------------- launcher ----------------
extern "C" void kernel_launch(void* const* d_in, const int* in_sizes, int n_in,
                              void* d_out, int out_size, void* d_ws, size_t ws_size,
                              hipStream_t stream)
{
    const float* x     = (const float*)d_in[0];
    const float* w_kan = (const float*)d_in[1];
    const float* d1    = (const float*)d_in[2];
    const float* d2    = (const float*)d_in[3];
    const float* d3    = (const float*)d_in[4];
    const float* w_rec = (const float*)d_in[5];
    const float* w_out = (const float*)d_in[6];
    float* out = (float*)d_out;

    char*   ws    = (char*)d_ws;
    __bf16* iin   = (__bf16*)ws;
    int*    Bpack = (int*)(ws + BPACK_OFF);
    float*  wrecT = (float*)(ws + WRECT_OFF);

    kan_pack<<<dim3((BPACK_WORDS + 255) / 256), 256, 0, stream>>>(
        w_kan, d1, d2, d3, w_rec, Bpack, wrecT);
    kan_gemm<<<dim3(4000), 64, 0, stream>>>(x, Bpack, iin);
    kan_scan<<<dim3(B_), 64, 0, stream>>>(iin, wrecT, w_out, out);
}